// Round 1
// baseline (454.613 us; speedup 1.0000x reference)
//
#include <hip/hip_runtime.h>

// ---------------------------------------------------------------------------
// MixHopConv fused: B=16, C=64, N=512, T=64, OUT_C=64, DEPTH=2
//   y[n,(b,oc,t)] = (W0 X)[n,col] + sum_j norm[n,j](W1 X)[j,col]
//                 + sum_j norm2[n,j](W2 X)[j,col] + bias[oc]
// ws layout:
//   [0, 1MB)        A bf16 [512][1024], 64B-block pre-swizzled (^((m&3)<<4))
//   [1MB, 2MB)      normf fp32 [512][512]
//   [2MB, 2MB+192MB) ZZ bf16 [1536][65536]; rows 0..511 = W0X (Z0),
//                    512..1023 = W1X, 1024..1535 = W2X
// ---------------------------------------------------------------------------

typedef float f32x4 __attribute__((ext_vector_type(4)));
typedef __bf16 bf16x8 __attribute__((ext_vector_type(8)));
typedef unsigned int u32x4 __attribute__((ext_vector_type(4)));

union Frag {
  bf16x8 b;
  u32x4 v4;
  unsigned long long u64[2];
  unsigned short us[8];
};

__device__ __forceinline__ unsigned short f2bf(float f) {  // RNE f32->bf16
  unsigned int u = __float_as_uint(f);
  u += 0x7fffu + ((u >> 16) & 1u);
  return (unsigned short)(u >> 16);
}
__device__ __forceinline__ float bf2f(unsigned short h) {
  return __uint_as_float(((unsigned int)h) << 16);
}

// pre-swizzled A byte address for element (m, k), row stride 2048B
__device__ __forceinline__ int a_byte(int m, int k) {
  return m * 2048 + ((k >> 5) << 6) + (((k & 31) << 1) ^ ((m & 3) << 4));
}

// ---------------- kernel 1a: row-normalize adj ----------------
__global__ __launch_bounds__(256) void k_norm(const float* __restrict__ adj,
                                              float* __restrict__ normf,
                                              char* __restrict__ Abf) {
  int i = blockIdx.x, tid = threadIdx.x;
  float v0 = adj[i * 512 + tid];
  float v1 = adj[i * 512 + 256 + tid];
  float s = v0 + v1;
#pragma unroll
  for (int off = 32; off >= 1; off >>= 1) s += __shfl_down(s, off);
  __shared__ float ps[4];
  if ((tid & 63) == 0) ps[tid >> 6] = s;
  __syncthreads();
  float inv = 1.0f / (ps[0] + ps[1] + ps[2] + ps[3] + 1e-6f);
  float n0 = v0 * inv, n1 = v1 * inv;
  normf[i * 512 + tid] = n0;
  normf[i * 512 + 256 + tid] = n1;
  *(unsigned short*)(Abf + a_byte(i, tid)) = f2bf(n0);
  *(unsigned short*)(Abf + a_byte(i, tid + 256)) = f2bf(n1);
}

// ---------------- kernel 1b: norm2 = norm @ norm ----------------
__global__ __launch_bounds__(256) void k_norm2(const float* __restrict__ normf,
                                               char* __restrict__ Abf) {
  int i0 = blockIdx.x * 4, tid = threadIdx.x;
  __shared__ float rows[4][512];
  for (int idx = tid; idx < 2048; idx += 256)
    rows[idx >> 9][idx & 511] = normf[(i0 + (idx >> 9)) * 512 + (idx & 511)];
  __syncthreads();
  float a[4][2] = {};
  for (int k = 0; k < 512; ++k) {
    float v0 = normf[k * 512 + tid];
    float v1 = normf[k * 512 + 256 + tid];
#pragma unroll
    for (int ii = 0; ii < 4; ++ii) {
      float r = rows[ii][k];
      a[ii][0] += r * v0;
      a[ii][1] += r * v1;
    }
  }
#pragma unroll
  for (int ii = 0; ii < 4; ++ii) {
    *(unsigned short*)(Abf + a_byte(i0 + ii, 512 + tid)) = f2bf(a[ii][0]);
    *(unsigned short*)(Abf + a_byte(i0 + ii, 512 + 256 + tid)) = f2bf(a[ii][1]);
  }
}

// ---------------- kernel 2: channel mix  Z = [W0;W1;W2] @ x_b ----------------
// grid = 16 b * 128 pos-tiles (256 pos each), 512 threads (8 waves, 2x4)
__global__ __launch_bounds__(512) void k_chmix(const float* __restrict__ x,
                                               const float* __restrict__ W,
                                               unsigned short* __restrict__ ZZ) {
  __shared__ __align__(16) char Wl[24576];  // [192 rows][128B], swizzled
  int tid = threadIdx.x;
  for (int i = tid; i < 6144; i += 512) {
    int row = i >> 5, cp = i & 31;
    int oc = row & 63, hop = row >> 6;
    float f0 = W[oc * 192 + hop * 64 + 2 * cp];
    float f1 = W[oc * 192 + hop * 64 + 2 * cp + 1];
    unsigned int pk = (unsigned int)f2bf(f0) | ((unsigned int)f2bf(f1) << 16);
    *(unsigned int*)(Wl + row * 128 + ((cp << 2) ^ ((row & 15) << 3))) = pk;
  }
  __syncthreads();
  int b = blockIdx.x >> 7;
  int pt = blockIdx.x & 127;
  int lane = tid & 63, wid = tid >> 6;
  int wm = wid >> 2, wp = wid & 3;
  int mbase = wm * 96;                  // oc' range 96 per wave-row
  int posbase = pt * 256 + wp * 64;     // 64 pos (= one n, all t) per wave-col
  int l15 = lane & 15, g = lane >> 4;
  const float* xb = x + b * (64 * 32768);
  f32x4 acc[6][4] = {};
#pragma unroll
  for (int kb = 0; kb < 2; ++kb) {
    Frag af[6];
#pragma unroll
    for (int mf = 0; mf < 6; ++mf) {
      int row = mbase + mf * 16 + l15;
      int sz = (row & 15) << 3;
      const char* base = Wl + row * 128;
      af[mf].u64[0] = *(const unsigned long long*)(base + (((kb << 6) + (g << 4)) ^ sz));
      af[mf].u64[1] = *(const unsigned long long*)(base + (((kb << 6) + (g << 4) + 8) ^ sz));
    }
#pragma unroll
    for (int nf = 0; nf < 4; ++nf) {
      int pos = posbase + nf * 16 + l15;
      Frag bf;
#pragma unroll
      for (int i = 0; i < 8; ++i) {
        int c = (kb << 5) + (g << 3) + i;
        bf.us[i] = f2bf(xb[c * 32768 + pos]);
      }
#pragma unroll
      for (int mf = 0; mf < 6; ++mf)
        acc[mf][nf] = __builtin_amdgcn_mfma_f32_16x16x32_bf16(af[mf].b, bf.b, acc[mf][nf], 0, 0, 0);
    }
  }
  int n = posbase >> 6;  // wave-uniform
  int colb = b * 4096;
#pragma unroll
  for (int mf = 0; mf < 6; ++mf) {
#pragma unroll
    for (int r = 0; r < 4; ++r) {
      int ocp = mbase + mf * 16 + g * 4 + r;
      int hop = ocp >> 6, oc = ocp & 63;
      unsigned short* dst = ZZ + (hop * 512 + n) * 65536 + colb + oc * 64;
#pragma unroll
      for (int nf = 0; nf < 4; ++nf) dst[nf * 16 + l15] = f2bf(acc[mf][nf][r]);
    }
  }
}

// ---------------- kernel 3: y = A @ ZZ[512:] + Z0 + bias ----------------
// M=512, N=65536, K=1024; BM=BN=128, BK=64; 256 threads (2x2 waves, 64x64 each)
__global__ __launch_bounds__(256) void k_gemm(const char* __restrict__ Abf,
                                              const unsigned short* __restrict__ ZZ,
                                              const float* __restrict__ bias,
                                              float* __restrict__ out) {
  __shared__ __align__(16) char lds[32768];
  char* Al = lds;          // [128 rows][128B] (content pre-swizzled in global)
  char* Bl = lds + 16384;  // [128 cols][128B] xor-swizzled
  int tid = threadIdx.x, lane = tid & 63, wid = tid >> 6;
  int mt = blockIdx.x & 3, nt = blockIdx.x >> 2;  // mt fastest: B-panel reuse
  int m0 = mt * 128, col0 = nt * 128;
  int wm = wid >> 1, wn = wid & 1;
  int l15 = lane & 15, g = lane >> 4;
  const unsigned short* Zb = ZZ + 512 * 65536;
  f32x4 acc[4][4] = {};
  int skp = tid >> 4;           // staging k-pair 0..15
  int sc0 = (tid & 15) * 8;     // staging col group
  for (int ks = 0; ks < 16; ++ks) {
    __syncthreads();
    // stage A tile (128x64 bf16 = 16KB) via global_load_lds width 16
#pragma unroll
    for (int ii = 0; ii < 4; ++ii) {
      int q = wid * 4 + ii;
      int row = q * 8 + (lane >> 3);
      const char* g_src = Abf + (m0 + row) * 2048 + ks * 128 + (lane & 7) * 16;
      __builtin_amdgcn_global_load_lds(
          (const __attribute__((address_space(1))) void*)g_src,
          (__attribute__((address_space(3))) void*)(Al + q * 1024), 16, 0, 0);
    }
    // stage B tile (64k x 128col) transposed into [col][k] with xor swizzle
#pragma unroll
    for (int rd = 0; rd < 2; ++rd) {
      int kp = skp + rd * 16;
      const unsigned short* s0 = Zb + (ks * 64 + 2 * kp) * 65536 + col0 + sc0;
      Frag L0, L1;
      L0.v4 = *(const u32x4*)s0;
      L1.v4 = *(const u32x4*)(s0 + 65536);
#pragma unroll
      for (int j = 0; j < 8; ++j) {
        int col = sc0 + j;
        int sz = (((col & 15) ^ ((col >> 3) & 15)) << 3);
        unsigned int pk = (unsigned int)L0.us[j] | ((unsigned int)L1.us[j] << 16);
        *(unsigned int*)(Bl + col * 128 + ((kp << 2) ^ sz)) = pk;
      }
    }
    __syncthreads();
#pragma unroll
    for (int kb = 0; kb < 2; ++kb) {
      Frag af[4];
#pragma unroll
      for (int mf = 0; mf < 4; ++mf) {
        int row = wm * 64 + mf * 16 + l15;
        af[mf] = *(const Frag*)(Al + row * 128 + (kb << 6) + ((g << 4) ^ ((row & 3) << 4)));
      }
#pragma unroll
      for (int nf = 0; nf < 4; ++nf) {
        int col = wn * 64 + nf * 16 + l15;
        int sz = (((col & 15) ^ ((col >> 3) & 15)) << 3);
        const char* base = Bl + col * 128;
        Frag bf;
        bf.u64[0] = *(const unsigned long long*)(base + (((kb << 6) + (g << 4)) ^ sz));
        bf.u64[1] = *(const unsigned long long*)(base + (((kb << 6) + (g << 4) + 8) ^ sz));
#pragma unroll
        for (int mf = 0; mf < 4; ++mf)
          acc[mf][nf] = __builtin_amdgcn_mfma_f32_16x16x32_bf16(af[mf].b, bf.b, acc[mf][nf], 0, 0, 0);
      }
    }
  }
  // epilogue: + Z0 + bias, write fp32 out (b,oc,n,t)
#pragma unroll
  for (int mf = 0; mf < 4; ++mf) {
#pragma unroll
    for (int r = 0; r < 4; ++r) {
      int n = m0 + wm * 64 + mf * 16 + g * 4 + r;
#pragma unroll
      for (int nf = 0; nf < 4; ++nf) {
        int col = col0 + wn * 64 + nf * 16 + l15;
        float v = acc[mf][nf][r] + bf2f(ZZ[n * 65536 + col]) + bias[(col >> 6) & 63];
        out[(col >> 6) * 32768 + n * 64 + (col & 63)] = v;
      }
    }
  }
}

extern "C" void kernel_launch(void* const* d_in, const int* in_sizes, int n_in,
                              void* d_out, int out_size, void* d_ws, size_t ws_size,
                              hipStream_t stream) {
  const float* x = (const float*)d_in[0];     // (16,64,512,64)
  const float* adj = (const float*)d_in[1];   // (512,512)
  const float* W = (const float*)d_in[2];     // (64,192)
  const float* bias = (const float*)d_in[3];  // (64)
  float* out = (float*)d_out;
  char* ws = (char*)d_ws;
  char* Abf = ws;                                        // 1 MB
  float* normf = (float*)(ws + (1 << 20));               // 1 MB
  unsigned short* ZZ = (unsigned short*)(ws + (2 << 20)); // 192 MB

  k_norm<<<512, 256, 0, stream>>>(adj, normf, Abf);
  k_norm2<<<128, 256, 0, stream>>>(normf, Abf);
  k_chmix<<<2048, 512, 0, stream>>>(x, W, ZZ);
  k_gemm<<<2048, 256, 0, stream>>>(Abf, ZZ, bias, out);
}

// Round 2
// 450.840 us; speedup vs baseline: 1.0084x; 1.0084x over previous
//
#include <hip/hip_runtime.h>

// ---------------------------------------------------------------------------
// MixHopConv: B=16, C=64, N=512, T=64, OUT_C=64, DEPTH=2
//   y[n,(b,oc,t)] = (W0 X)[n,col] + sum_j norm[n,j](W1 X)[j,col]
//                 + sum_j norm2[n,j](W2 X)[j,col] + bias[oc]
// ws layout:
//   [0, 1MB)         A bf16 [512][1024]; 128B blocks of 64k, 16B-unit swizzle by row&7
//   [1MB, 1.5MB)     Nb  bf16 [512][512] row-major (norm)
//   [1.5MB, 2MB)     NbT bf16 [512][512] (norm^T)
//   [2MB, 2MB+192MB) ZZp u32 [768 kp][65536 col]; kp = (hop*512+n)/2,
//                    u32 = (bf16 k=2kp | bf16 k=2kp+1 << 16)
// ---------------------------------------------------------------------------

typedef float f32x4 __attribute__((ext_vector_type(4)));
typedef __bf16 bf16x8 __attribute__((ext_vector_type(8)));
typedef unsigned int u32x4 __attribute__((ext_vector_type(4)));

union Frag {
  bf16x8 b;
  u32x4 v4;
  unsigned long long u64[2];
  unsigned short us[8];
  __bf16 h[8];
};

__device__ __forceinline__ unsigned short f2bf(float f) {  // RNE f32->bf16
  unsigned int u = __float_as_uint(f);
  u += 0x7fffu + ((u >> 16) & 1u);
  return (unsigned short)(u >> 16);
}
__device__ __forceinline__ float bf2f(unsigned int h) {
  return __uint_as_float(h << 16);
}
__device__ __forceinline__ unsigned int pk2(float lo, float hi) {  // 2xbf16 pack
  union { __bf16 h[2]; unsigned int u; } t;
  t.h[0] = (__bf16)lo; t.h[1] = (__bf16)hi;
  return t.u;
}

// pre-swizzled A byte address for element (m, k): 128B block per 64 k,
// 16B units XOR'd by row&7 (8 units -> all 32 banks on frag reads)
__device__ __forceinline__ int a_byte(int m, int k) {
  return m * 2048 + ((k >> 6) << 7) + ((((k >> 3) & 7) ^ (m & 7)) << 4) + (k & 7) * 2;
}

// ---------------- kernel 1a: row-normalize adj ----------------
__global__ __launch_bounds__(256) void k_norm(const float* __restrict__ adj,
                                              char* __restrict__ Abf,
                                              unsigned short* __restrict__ Nb,
                                              unsigned short* __restrict__ NbT) {
  int i = blockIdx.x, tid = threadIdx.x;
  float v0 = adj[i * 512 + tid];
  float v1 = adj[i * 512 + 256 + tid];
  float s = v0 + v1;
#pragma unroll
  for (int off = 32; off >= 1; off >>= 1) s += __shfl_down(s, off);
  __shared__ float ps[4];
  if ((tid & 63) == 0) ps[tid >> 6] = s;
  __syncthreads();
  float inv = 1.0f / (ps[0] + ps[1] + ps[2] + ps[3] + 1e-6f);
  unsigned short b0 = f2bf(v0 * inv), b1 = f2bf(v1 * inv);
  Nb[i * 512 + tid] = b0;
  Nb[i * 512 + 256 + tid] = b1;
  NbT[tid * 512 + i] = b0;
  NbT[(tid + 256) * 512 + i] = b1;
  *(unsigned short*)(Abf + a_byte(i, tid)) = b0;
  *(unsigned short*)(Abf + a_byte(i, tid + 256)) = b1;
}

// ---------------- kernel 1b: norm2 = norm @ norm (bf16 MFMA) ----------------
// 16 blocks (4x4 of 128-tiles), 256 thr, 4 waves 2x2, frags direct from L2
__global__ __launch_bounds__(256) void k_norm2(const unsigned short* __restrict__ Nb,
                                               const unsigned short* __restrict__ NbT,
                                               char* __restrict__ Abf) {
  int tid = threadIdx.x, lane = tid & 63, wid = tid >> 6;
  int bm = blockIdx.x & 3, bn = blockIdx.x >> 2;
  int wm = wid >> 1, wn = wid & 1;
  int l15 = lane & 15, g = lane >> 4;
  const char* Ab = (const char*)Nb;
  const char* Bb = (const char*)NbT;
  f32x4 acc[4][4] = {};
  for (int ks = 0; ks < 16; ++ks) {
    Frag af[4], bf[4];
#pragma unroll
    for (int mf = 0; mf < 4; ++mf)
      af[mf] = *(const Frag*)(Ab + (bm * 128 + wm * 64 + mf * 16 + l15) * 1024 + ks * 64 + g * 16);
#pragma unroll
    for (int nf = 0; nf < 4; ++nf)
      bf[nf] = *(const Frag*)(Bb + (bn * 128 + wn * 64 + nf * 16 + l15) * 1024 + ks * 64 + g * 16);
#pragma unroll
    for (int mf = 0; mf < 4; ++mf)
#pragma unroll
      for (int nf = 0; nf < 4; ++nf)
        acc[mf][nf] = __builtin_amdgcn_mfma_f32_16x16x32_bf16(af[mf].b, bf[nf].b, acc[mf][nf], 0, 0, 0);
  }
#pragma unroll
  for (int mf = 0; mf < 4; ++mf)
#pragma unroll
    for (int nf = 0; nf < 4; ++nf)
#pragma unroll
      for (int r = 0; r < 4; ++r) {
        int i = bm * 128 + wm * 64 + mf * 16 + g * 4 + r;
        int j = bn * 128 + wn * 64 + nf * 16 + l15;
        *(unsigned short*)(Abf + a_byte(i, 512 + j)) = f2bf(acc[mf][nf][r]);
      }
}

// ---------------- kernel 2: Z = [W0;W1;W2] @ x_b, k-pair-interleaved out ----
// grid = 16 b * 128 pt (4 n x 64 t each), 512 threads (8 waves: 2 m x 4)
// wave wp: n-pair (wp>>1), t-half (wp&1); frag cols = 2n x 16t per pass
__global__ __launch_bounds__(512) void k_chmix(const float* __restrict__ x,
                                               const float* __restrict__ W,
                                               unsigned int* __restrict__ ZZp) {
  __shared__ __align__(16) char Wl[24576];  // [192 rows][128B], swizzled
  int tid = threadIdx.x;
  for (int i = tid; i < 6144; i += 512) {
    int row = i >> 5, cp = i & 31;
    int oc = row & 63, hop = row >> 6;
    unsigned int pk = (unsigned int)f2bf(W[oc * 192 + hop * 64 + 2 * cp]) |
                      ((unsigned int)f2bf(W[oc * 192 + hop * 64 + 2 * cp + 1]) << 16);
    *(unsigned int*)(Wl + row * 128 + ((cp << 2) ^ ((row & 15) << 3))) = pk;
  }
  __syncthreads();
  int b = blockIdx.x >> 7, pt = blockIdx.x & 127;
  int lane = tid & 63, wid = tid >> 6;
  int wm = wid >> 2, wp = wid & 3;
  int mbase = wm * 96;
  int n0 = pt * 4 + (wp >> 1) * 2;
  int t0 = (wp & 1) * 32;
  int l15 = lane & 15, g = lane >> 4;
  int kpb = pt * 2 + (wp >> 1);
  const float* xb = x + b * (64 * 32768);
#pragma unroll
  for (int p = 0; p < 2; ++p) {  // t-quarter pass: t = t0 + p*16 + l15
    int tt = t0 + p * 16 + l15;
    f32x4 acc[6][2] = {};
#pragma unroll
    for (int kb = 0; kb < 2; ++kb) {
      Frag af[6];
#pragma unroll
      for (int mf = 0; mf < 6; ++mf) {
        int row = mbase + mf * 16 + l15;
        int sz = (row & 15) << 3;
        const char* base = Wl + row * 128;
        af[mf].u64[0] = *(const unsigned long long*)(base + ((((kb << 6) + (g << 4))) ^ sz));
        af[mf].u64[1] = *(const unsigned long long*)(base + ((((kb << 6) + (g << 4) + 8)) ^ sz));
      }
#pragma unroll
      for (int nn = 0; nn < 2; ++nn) {  // n = n0 + nn
        const float* xp = xb + (n0 + nn) * 64 + tt;
        Frag bf;
#pragma unroll
        for (int i = 0; i < 8; ++i) {
          int c = kb * 32 + g * 8 + i;
          bf.h[i] = (__bf16)xp[c * 32768];
        }
#pragma unroll
        for (int mf = 0; mf < 6; ++mf)
          acc[mf][nn] = __builtin_amdgcn_mfma_f32_16x16x32_bf16(af[mf].b, bf.b, acc[mf][nn], 0, 0, 0);
      }
    }
#pragma unroll
    for (int mf = 0; mf < 6; ++mf)
#pragma unroll
      for (int r = 0; r < 4; ++r) {
        int ocp = mbase + mf * 16 + g * 4 + r;
        int hop = ocp >> 6, oc = ocp & 63;
        ZZp[(hop * 256 + kpb) * 65536 + b * 4096 + oc * 64 + t0 + p * 16 + l15] =
            pk2(acc[mf][0][r], acc[mf][1][r]);
      }
  }
}

// ---------------- kernel 3: y = A @ ZZ[512:] + Z0 + bias ----------------
// M=512, N=65536, K=1024; BM=BN=128, BK=64; 512 thr (2x4 waves, 64x32 each);
// double-buffered LDS, prefetch-before-compute (2-phase), XCD-chunked grid
__global__ __launch_bounds__(512) void k_gemm(const char* __restrict__ Abf,
                                              const unsigned int* __restrict__ ZZp,
                                              const float* __restrict__ bias,
                                              float* __restrict__ out) {
  __shared__ __align__(16) char lds[65536];  // buf c: A at c*32768, B at +16384
  int tid = threadIdx.x, lane = tid & 63, wid = tid >> 6;
  int p = blockIdx.x;
  int o = (p & 7) * 256 + (p >> 3);  // XCD-chunked: mt-siblings share an XCD
  int mt = o & 3, nt = o >> 2;
  int m0 = mt * 128, col0 = nt * 128;
  int wm = wid >> 2, wn = wid & 3;
  int l15 = lane & 15, g = lane >> 4;
  int colg = tid & 15, kpl = tid >> 4;  // staging: 32 kp rows x 16 col groups
  const unsigned int* Zs = ZZp + (256 + kpl) * 65536 + col0 + colg * 4;
  f32x4 acc[4][2] = {};
  u32x4 breg[2];

#define LOADB(ks)                                                     \
  {                                                                   \
    breg[0] = *(const u32x4*)(Zs + (ks) * 32 * 65536);                \
    breg[1] = *(const u32x4*)(Zs + (ks) * 32 * 65536 + 64);           \
  }
#define GLOADA(ks, Ad)                                                        \
  {                                                                           \
    _Pragma("unroll") for (int s = 0; s < 2; ++s) {                           \
      const char* gs = Abf + (m0 + s * 64 + (tid >> 3)) * 2048 + (ks) * 128 + \
                       (tid & 7) * 16;                                        \
      __builtin_amdgcn_global_load_lds(                                       \
          (const __attribute__((address_space(1))) void*)gs,                  \
          (__attribute__((address_space(3))) void*)((Ad) + s * 8192 + tid * 16), \
          16, 0, 0);                                                          \
    }                                                                         \
  }
#define STOREB(Bd)                                                            \
  {                                                                           \
    _Pragma("unroll") for (int cc = 0; cc < 2; ++cc)                          \
        _Pragma("unroll") for (int j = 0; j < 4; ++j) {                       \
      int col = colg * 4 + cc * 64 + j;                                       \
      int key = (col & 7) ^ ((col >> 3) & 7);                                 \
      *(unsigned int*)((Bd) + col * 128 + ((((kpl >> 2) ^ key)) << 4) +       \
                       ((kpl & 3) << 2)) = breg[cc][j];                       \
    }                                                                         \
  }

  // prologue: stage tile 0 into buf0
  LOADB(0);
  GLOADA(0, lds);
  STOREB(lds + 16384);
  __syncthreads();

#pragma unroll 2
  for (int ks = 0; ks < 16; ++ks) {
    char* Ac = lds + (ks & 1) * 32768;
    char* Bc = Ac + 16384;
    char* An = lds + ((ks & 1) ^ 1) * 32768;
    if (ks < 15) {
      LOADB(ks + 1);       // issue B global loads early (hide under MFMA)
      GLOADA(ks + 1, An);  // async A -> next LDS buffer
    }
#pragma unroll
    for (int kb = 0; kb < 2; ++kb) {
      Frag af[4], bf[2];
#pragma unroll
      for (int mf = 0; mf < 4; ++mf) {
        int row = wm * 64 + mf * 16 + l15;
        af[mf] = *(const Frag*)(Ac + row * 128 + (((kb * 4 + g) ^ (row & 7)) << 4));
      }
#pragma unroll
      for (int nf = 0; nf < 2; ++nf) {
        int col = wn * 32 + nf * 16 + l15;
        int key = (col & 7) ^ ((col >> 3) & 7);
        bf[nf] = *(const Frag*)(Bc + col * 128 + (((kb * 4 + g) ^ key) << 4));
      }
#pragma unroll
      for (int mf = 0; mf < 4; ++mf)
#pragma unroll
        for (int nf = 0; nf < 2; ++nf)
          acc[mf][nf] = __builtin_amdgcn_mfma_f32_16x16x32_bf16(af[mf].b, bf[nf].b, acc[mf][nf], 0, 0, 0);
    }
    if (ks < 15) STOREB(An + 16384);
    __syncthreads();
  }
#undef LOADB
#undef GLOADA
#undef STOREB

  // epilogue: + Z0 + bias, write fp32 out (b,oc,n,t)
#pragma unroll
  for (int mf = 0; mf < 4; ++mf) {
    int nb0 = (m0 >> 1) + wm * 32 + mf * 8 + g * 2;
    int n0e = m0 + wm * 64 + mf * 16 + g * 4;
#pragma unroll
    for (int nf = 0; nf < 2; ++nf) {
      int col = col0 + wn * 32 + nf * 16 + l15;
      unsigned int z01 = ZZp[nb0 * 65536 + col];
      unsigned int z23 = ZZp[(nb0 + 1) * 65536 + col];
      float bv = bias[(col >> 6) & 63];
      float* ob = out + (col >> 6) * 32768 + (col & 63);
      ob[(n0e + 0) * 64] = acc[mf][nf][0] + bf2f(z01 & 0xffffu) + bv;
      ob[(n0e + 1) * 64] = acc[mf][nf][1] + bf2f(z01 >> 16) + bv;
      ob[(n0e + 2) * 64] = acc[mf][nf][2] + bf2f(z23 & 0xffffu) + bv;
      ob[(n0e + 3) * 64] = acc[mf][nf][3] + bf2f(z23 >> 16) + bv;
    }
  }
}

extern "C" void kernel_launch(void* const* d_in, const int* in_sizes, int n_in,
                              void* d_out, int out_size, void* d_ws, size_t ws_size,
                              hipStream_t stream) {
  const float* x = (const float*)d_in[0];     // (16,64,512,64)
  const float* adj = (const float*)d_in[1];   // (512,512)
  const float* W = (const float*)d_in[2];     // (64,192)
  const float* bias = (const float*)d_in[3];  // (64)
  float* out = (float*)d_out;
  char* ws = (char*)d_ws;
  char* Abf = ws;                                                   // 1 MB
  unsigned short* Nb = (unsigned short*)(ws + (1 << 20));           // 512 KB
  unsigned short* NbT = (unsigned short*)(ws + (1 << 20) + (1 << 19));  // 512 KB
  unsigned int* ZZp = (unsigned int*)(ws + (2 << 20));              // 192 MB

  k_norm<<<512, 256, 0, stream>>>(adj, Abf, Nb, NbT);
  k_norm2<<<16, 256, 0, stream>>>(Nb, NbT, Abf);
  k_chmix<<<2048, 512, 0, stream>>>(x, W, ZZp);
  k_gemm<<<2048, 512, 0, stream>>>(Abf, ZZp, bias, out);
}